// Round 14
// baseline (90.256 us; speedup 1.0000x reference)
//
#include <hip/hip_runtime.h>
#include <hip/hip_fp16.h>
#include <math.h>

typedef _Float16 f16;
typedef _Float16 f16x8 __attribute__((ext_vector_type(8)));
typedef _Float16 f16x4v __attribute__((ext_vector_type(4)));
typedef float f32x4 __attribute__((ext_vector_type(4)));

#define BATCH   2
#define LSEQ    1024
#define BLTOT   2048
#define DMODEL  512
#define NHEAD   8
#define PDIM    1824          // 512*3 + 96*3
#define AW      96            // QK augmented width (78 used, padded to 96)
#define VW      80            // V/O width (76 used, padded to 80)
#define ODIM    608
#define NSPLIT  2
#define OCPSTR  1310720       // f16 elements per split of OCp (16*1024*80)

// ---------------------------------------------------------------------------
// Prep: WallT tiles only (912 blocks).
// ---------------------------------------------------------------------------
__global__ __launch_bounds__(256)
void prep_kernel(const float* __restrict__ Wq, const float* __restrict__ Wk,
                 const float* __restrict__ Wv, const float* __restrict__ Wqp,
                 const float* __restrict__ Wkp, const float* __restrict__ Wvp,
                 f16* __restrict__ WallT)
{
    const int blk = blockIdx.x;
    const int t = threadIdx.x;
    __shared__ float tile[32][33];

    const int n0 = (blk % 57) * 32, k0 = (blk / 57) * 32;
    const float* src; int ld, nc0;
    if      (n0 < 512)  { src = Wq;  ld = 512; nc0 = n0; }
    else if (n0 < 1024) { src = Wk;  ld = 512; nc0 = n0 - 512; }
    else if (n0 < 1536) { src = Wv;  ld = 512; nc0 = n0 - 1024; }
    else if (n0 < 1632) { src = Wqp; ld = 96;  nc0 = n0 - 1536; }
    else if (n0 < 1728) { src = Wkp; ld = 96;  nc0 = n0 - 1632; }
    else                { src = Wvp; ld = 96;  nc0 = n0 - 1728; }
#pragma unroll
    for (int i = 0; i < 4; ++i) {
        const int idx2 = t + i * 256;
        const int kl = idx2 >> 5, nl = idx2 & 31;
        tile[kl][nl] = src[(long long)(k0 + kl) * ld + nc0 + nl];
    }
    __syncthreads();
#pragma unroll
    for (int i = 0; i < 4; ++i) {
        const int idx2 = t + i * 256;
        const int nl = idx2 >> 5, kl = idx2 & 31;
        WallT[(long long)(n0 + nl) * 512 + k0 + kl] = (f16)tile[kl][nl];
    }
}

// ---------------------------------------------------------------------------
// Projection GEMM (+WoT transpose side-blocks). y<32: P = s(f32) @ WallT^T.
// y in {32,33}: 8 WoT transpose tiles each. Tile 64x96, BK=32, dbuf.
// ---------------------------------------------------------------------------
__global__ __launch_bounds__(256)
void proj_kernel(const float* __restrict__ S, const f16* __restrict__ Bt,
                 const float* __restrict__ Wo, f16* __restrict__ WoT,
                 f16* __restrict__ P)
{
    __shared__ f16 As[2][64][40];
    __shared__ f16 Bs[2][96][40];
    const int t = threadIdx.x;

    if (blockIdx.y >= 32) {
        float (*tile)[33] = (float(*)[33])&As[0][0][0];
        const int base = (blockIdx.x + (blockIdx.y - 32) * 19) * 8;
#pragma unroll 1
        for (int it = 0; it < 8; ++it) {
            const int idx = base + it;
            const int n0 = (idx & 15) * 32, k0 = (idx >> 4) * 32;
#pragma unroll
            for (int i = 0; i < 4; ++i) {
                const int idx2 = t + i * 256;
                const int kl = idx2 >> 5, nl = idx2 & 31;
                tile[kl][nl] = Wo[(long long)(k0 + kl) * 512 + n0 + nl];
            }
            __syncthreads();
#pragma unroll
            for (int i = 0; i < 4; ++i) {
                const int idx2 = t + i * 256;
                const int nl = idx2 >> 5, kl = idx2 & 31;
                WoT[(long long)(n0 + nl) * 608 + k0 + kl] = (f16)tile[kl][nl];
            }
            __syncthreads();
        }
        return;
    }

    const int w = t >> 6, lane = t & 63, l15 = lane & 15, lhi = lane >> 4;
    const int row0 = blockIdx.y * 64, col0 = blockIdx.x * 96;
    const int ar = t >> 2, ac = t & 3;
    const int K = 512;

    f32x4 acc[6];
#pragma unroll
    for (int n = 0; n < 6; ++n) acc[n] = (f32x4){0.f, 0.f, 0.f, 0.f};

    float4 a0, a1;
    f16x8 bR[2];
    a0 = *(const float4*)&S[(long long)(row0 + ar) * K + ac * 8];
    a1 = *(const float4*)&S[(long long)(row0 + ar) * K + ac * 8 + 4];
#pragma unroll
    for (int i = 0; i < 2; ++i) {
        const int cid = t + i * 256;
        if (cid < 384) {
            const int br = cid >> 2, bc = cid & 3;
            bR[i] = *(const f16x8*)&Bt[(long long)(col0 + br) * K + bc * 8];
        }
    }
    {
        f16x8 v = { (f16)a0.x, (f16)a0.y, (f16)a0.z, (f16)a0.w,
                    (f16)a1.x, (f16)a1.y, (f16)a1.z, (f16)a1.w };
        *(f16x8*)&As[0][ar][ac * 8] = v;
    }
#pragma unroll
    for (int i = 0; i < 2; ++i) {
        const int cid = t + i * 256;
        if (cid < 384) *(f16x8*)&Bs[0][cid >> 2][(cid & 3) * 8] = bR[i];
    }
    __syncthreads();

    for (int st = 0; st < 16; ++st) {
        const int cur = st & 1;
        if (st + 1 < 16) {
            const int k0 = (st + 1) << 5;
            a0 = *(const float4*)&S[(long long)(row0 + ar) * K + k0 + ac * 8];
            a1 = *(const float4*)&S[(long long)(row0 + ar) * K + k0 + ac * 8 + 4];
#pragma unroll
            for (int i = 0; i < 2; ++i) {
                const int cid = t + i * 256;
                if (cid < 384) {
                    const int br = cid >> 2, bc = cid & 3;
                    bR[i] = *(const f16x8*)&Bt[(long long)(col0 + br) * K + k0 + bc * 8];
                }
            }
        }
        f16x8 af = *(const f16x8*)&As[cur][w * 16 + l15][lhi * 8];
        f16x8 bf[6];
#pragma unroll
        for (int n = 0; n < 6; ++n)
            bf[n] = *(const f16x8*)&Bs[cur][n * 16 + l15][lhi * 8];
#pragma unroll
        for (int n = 0; n < 6; ++n)
            acc[n] = __builtin_amdgcn_mfma_f32_16x16x32_f16(af, bf[n], acc[n], 0, 0, 0);
        if (st + 1 < 16) {
            f16x8 v = { (f16)a0.x, (f16)a0.y, (f16)a0.z, (f16)a0.w,
                        (f16)a1.x, (f16)a1.y, (f16)a1.z, (f16)a1.w };
            *(f16x8*)&As[cur ^ 1][ar][ac * 8] = v;
#pragma unroll
            for (int i = 0; i < 2; ++i) {
                const int cid = t + i * 256;
                if (cid < 384) *(f16x8*)&Bs[cur ^ 1][cid >> 2][(cid & 3) * 8] = bR[i];
            }
        }
        __syncthreads();
    }

    const int row = row0 + w * 16 + lhi * 4;
#pragma unroll
    for (int n = 0; n < 6; ++n) {
        const int col = col0 + n * 16 + l15;
#pragma unroll
        for (int r = 0; r < 4; ++r)
            P[(long long)(row + r) * PDIM + col] = (f16)acc[n][r];
    }
}

// ---------------------------------------------------------------------------
// Double-buffered MFMA f16 GEMM (out projection).  C = A @ Bt^T.
// ---------------------------------------------------------------------------
template<int BN, bool OUT16>
__global__ __launch_bounds__(256)
void gemm2_kernel(const f16* __restrict__ A, const f16* __restrict__ Bt,
                  void* __restrict__ Cout, int K, int ldc)
{
    constexpr int BCH = (BN * 4 + 255) / 256;
    __shared__ f16 As[2][64][40];
    __shared__ f16 Bs[2][BN][40];
    const int t = threadIdx.x;
    const int w = t >> 6, lane = t & 63, l15 = lane & 15, lhi = lane >> 4;
    const int row0 = blockIdx.y * 64, col0 = blockIdx.x * BN;
    const int ar = t >> 2, ac = t & 3;

    f32x4 acc[BN / 16];
#pragma unroll
    for (int n = 0; n < BN / 16; ++n) acc[n] = (f32x4){0.f, 0.f, 0.f, 0.f};

    const int nsteps = K >> 5;

    f16x8 aR;
    f16x8 bR[BCH];
    aR = *(const f16x8*)&A[(long long)(row0 + ar) * K + ac * 8];
#pragma unroll
    for (int i = 0; i < BCH; ++i) {
        const int cid = t + i * 256;
        if (cid < BN * 4) {
            const int br = cid >> 2, bc = cid & 3;
            bR[i] = *(const f16x8*)&Bt[(long long)(col0 + br) * K + bc * 8];
        }
    }
    *(f16x8*)&As[0][ar][ac * 8] = aR;
#pragma unroll
    for (int i = 0; i < BCH; ++i) {
        const int cid = t + i * 256;
        if (cid < BN * 4) *(f16x8*)&Bs[0][cid >> 2][(cid & 3) * 8] = bR[i];
    }
    __syncthreads();

    for (int st = 0; st < nsteps; ++st) {
        const int cur = st & 1;
        if (st + 1 < nsteps) {
            const int k0 = (st + 1) << 5;
            aR = *(const f16x8*)&A[(long long)(row0 + ar) * K + k0 + ac * 8];
#pragma unroll
            for (int i = 0; i < BCH; ++i) {
                const int cid = t + i * 256;
                if (cid < BN * 4) {
                    const int br = cid >> 2, bc = cid & 3;
                    bR[i] = *(const f16x8*)&Bt[(long long)(col0 + br) * K + k0 + bc * 8];
                }
            }
        }
        f16x8 af = *(const f16x8*)&As[cur][w * 16 + l15][lhi * 8];
        f16x8 bf[BN / 16];
#pragma unroll
        for (int n = 0; n < BN / 16; ++n)
            bf[n] = *(const f16x8*)&Bs[cur][n * 16 + l15][lhi * 8];
#pragma unroll
        for (int n = 0; n < BN / 16; ++n)
            acc[n] = __builtin_amdgcn_mfma_f32_16x16x32_f16(af, bf[n], acc[n], 0, 0, 0);
        if (st + 1 < nsteps) {
            *(f16x8*)&As[cur ^ 1][ar][ac * 8] = aR;
#pragma unroll
            for (int i = 0; i < BCH; ++i) {
                const int cid = t + i * 256;
                if (cid < BN * 4) *(f16x8*)&Bs[cur ^ 1][cid >> 2][(cid & 3) * 8] = bR[i];
            }
        }
        __syncthreads();
    }

    const int row = row0 + w * 16 + lhi * 4;
#pragma unroll
    for (int n = 0; n < BN / 16; ++n) {
        const int col = col0 + n * 16 + l15;
#pragma unroll
        for (int r = 0; r < 4; ++r) {
            if (OUT16) ((f16*)Cout)[(long long)(row + r) * ldc + col] = (f16)acc[n][r];
            else       ((float*)Cout)[(long long)(row + r) * ldc + col] = acc[n][r];
        }
    }
}

// ---------------------------------------------------------------------------
// Fused augment+transpose. Grid (16 l-tiles of 64, 16 bh). Produces
// QA/KA f16 [bh][1024][96], VCT f16 [bh][80][1024]. KOFF folded into
// KA cols 76/77 (hi+residual, exact).
// ---------------------------------------------------------------------------
__global__ __launch_bounds__(256)
void build_aug2_kernel(const f16* __restrict__ P, const float* __restrict__ Rm,
                       const float* __restrict__ tr, const float* __restrict__ wC,
                       f16* __restrict__ QA, f16* __restrict__ KA,
                       f16* __restrict__ VCT)
{
    const int l0 = blockIdx.x * 64;
    const int bh = blockIdx.y;
    const int b = bh >> 3, h = bh & 7;
    const int t = threadIdx.x;

    __shared__ float Rl[64][9];
    __shared__ float trl[64][3];
    __shared__ f16 gq[64][12];
    __shared__ f16 gk[64][12];
    __shared__ float k2[64][4];
    __shared__ f16 Vt[VW][72];
    __shared__ float wcs;

    const long long blbase = (long long)b * LSEQ + l0;

    for (int i = t; i < 64 * 9; i += 256) Rl[i / 9][i % 9] = Rm[blbase * 9 + i];
    for (int i = t; i < 64 * 3; i += 256) trl[i / 3][i % 3] = tr[blbase * 3 + i];
    if (t == 0) { float x = wC[h]; wcs = log1pf(expf(x)); }
    __syncthreads();
    const float wc = wcs;

    for (int i = t; i < 768; i += 256) {
        const int l = i / 12, pp = i - l * 12;
        const int proj = pp >> 2, p = pp & 3;
        const f16* src = P + (blbase + l) * PDIM + 1536 + proj * 96 + h * 12 + p * 3;
        const float x = (float)src[0], y = (float)src[1], z = (float)src[2];
        const float gx = Rl[l][0]*x + Rl[l][1]*y + Rl[l][2]*z + trl[l][0];
        const float gy = Rl[l][3]*x + Rl[l][4]*y + Rl[l][5]*z + trl[l][1];
        const float gz = Rl[l][6]*x + Rl[l][7]*y + Rl[l][8]*z + trl[l][2];
        if (proj == 0) {
            gq[l][p * 3 + 0] = (f16)(wc * gx);
            gq[l][p * 3 + 1] = (f16)(wc * gy);
            gq[l][p * 3 + 2] = (f16)(wc * gz);
        } else if (proj == 1) {
            gk[l][p * 3 + 0] = (f16)gx;
            gk[l][p * 3 + 1] = (f16)gy;
            gk[l][p * 3 + 2] = (f16)gz;
            k2[l][p] = gx * gx + gy * gy + gz * gz;
        } else {
            Vt[64 + p * 3 + 0][l] = (f16)gx;
            Vt[64 + p * 3 + 1][l] = (f16)gy;
            Vt[64 + p * 3 + 2][l] = (f16)gz;
        }
    }
    for (int i = t; i < 512; i += 256) {
        const int l = i >> 3, ch = i & 7;
        f16x8 v = *(const f16x8*)&P[(blbase + l) * PDIM + 1024 + h * 64 + ch * 8];
#pragma unroll
        for (int j = 0; j < 8; ++j) Vt[ch * 8 + j][l] = v[j];
    }
    for (int i = t; i < 36; i += 256) {
        const int r = 76 + i / 9, ch = i % 9;
        *(f16x8*)&Vt[r][ch * 8] = (f16x8){0,0,0,0,0,0,0,0};
    }
    __syncthreads();

    for (int i = t; i < 768; i += 256) {
        const int l = i / 12, ch = i - l * 12;
        const long long prow = (blbase + l) * PDIM;
        const long long orow = ((long long)bh * LSEQ + l0 + l) * AW;
        f16x8 q, k;
        if (ch < 8) {
            f16x8 qv = *(const f16x8*)&P[prow + h * 64 + ch * 8];
            f16x8 kv = *(const f16x8*)&P[prow + 512 + h * 64 + ch * 8];
            q = qv * (f16)0.125f;
            k = kv;
        } else if (ch == 8) {
#pragma unroll
            for (int j = 0; j < 8; ++j) { q[j] = gq[l][j]; k[j] = gk[l][j]; }
        } else if (ch == 9) {
            const float koff = 0.5f * wc * (k2[l][0] + k2[l][1] + k2[l][2] + k2[l][3]);
            const f16 kh = (f16)koff;
            const float kres = koff - (float)kh;
#pragma unroll
            for (int j = 0; j < 4; ++j) { q[j] = gq[l][8 + j]; k[j] = gk[l][8 + j]; }
            q[4] = (f16)1.f; k[4] = -kh;          // col 76
            q[5] = (f16)1.f; k[5] = (f16)(-kres); // col 77
            q[6] = (f16)0.f; k[6] = (f16)0.f;
            q[7] = (f16)0.f; k[7] = (f16)0.f;
        } else {
            q = (f16x8){0,0,0,0,0,0,0,0};
            k = (f16x8){0,0,0,0,0,0,0,0};
        }
        *(f16x8*)&QA[orow + ch * 8] = q;
        *(f16x8*)&KA[orow + ch * 8] = k;
    }
    for (int i = t; i < 640; i += 256) {
        const int c = i >> 3, lg = i & 7;
        *(f16x8*)&VCT[((long long)bh * VW + c) * LSEQ + l0 + lg * 8] =
            *(const f16x8*)&Vt[c][lg * 8];
    }
}

// ---------------------------------------------------------------------------
// Fused flash attention, split-KV, reg-prefetch dbuf, defer-max, swapped QK^T,
// IN-BLOCK KV SPLIT: wave w handles q-rows (w&1)*32..+32 (2 m-frags) and
// kv-half (w>>1) of each 128-tile. 2x MFMA per LDS read vs prior layout.
// Epilogue merges the two halves through LDS, then writes O + LSE.
// Grid (16 q-tiles, 16 bh, NSPLIT).
// ---------------------------------------------------------------------------
__global__ __launch_bounds__(256, 2)
void attn_kernel(const f16* __restrict__ QA, const f16* __restrict__ KA,
                 const f16* __restrict__ VCT,
                 f16* __restrict__ OCp, float* __restrict__ LSE)
{
    const int bh = blockIdx.y;
    const int q0 = blockIdx.x * 64;
    const int z  = blockIdx.z;
    const int t = threadIdx.x;
    const int w = t >> 6, lane = t & 63, l15 = lane & 15, lhi = lane >> 4;
    const int wsub = w & 1;      // m-block: rows wsub*32 .. +32
    const int kh   = w >> 1;     // kv half of each 128-tile

    __shared__ f16 Ks[128][104];
    __shared__ f16 Vs[VW][136];
    __shared__ f16 Ps[64][136];

    f16x8 qf[2][3];
#pragma unroll
    for (int m = 0; m < 2; ++m) {
        const f16* qb = QA + ((long long)bh * LSEQ + q0 + wsub * 32 + m * 16 + l15) * AW;
#pragma unroll
        for (int ks = 0; ks < 3; ++ks)
            qf[m][ks] = *(const f16x8*)(qb + ks * 32 + lhi * 8);
    }

    f32x4 Oacc[2][5];
#pragma unroll
    for (int m = 0; m < 2; ++m)
#pragma unroll
        for (int nv = 0; nv < 5; ++nv) Oacc[m][nv] = (f32x4){0.f, 0.f, 0.f, 0.f};
    float M[2] = {-1e30f, -1e30f}, L[2] = {0.f, 0.f};

    const f16* kgbase = KA + (long long)bh * LSEQ * AW;
    const f16* vgbase = VCT + (long long)bh * VW * LSEQ;

    const int kvbeg = z * (LSEQ / NSPLIT);
    const int kvend = kvbeg + LSEQ / NSPLIT;

#pragma unroll
    for (int i = 0; i < 6; ++i) {
        const int cid = t + i * 256;
        const int r = cid / 12, c = cid - r * 12;
        *(f16x8*)&Ks[r][c * 8] = *(const f16x8*)(kgbase + (long long)(kvbeg + r) * AW + c * 8);
    }
#pragma unroll
    for (int i = 0; i < 5; ++i) {
        const int cid = t + i * 256;
        const int r = cid >> 4, c = cid & 15;
        *(f16x8*)&Vs[r][c * 8] = *(const f16x8*)(vgbase + (long long)r * LSEQ + kvbeg + c * 8);
    }
    __syncthreads();

    for (int kv0 = kvbeg; kv0 < kvend; kv0 += 128) {
        const bool more = (kv0 + 128 < kvend);
        f16x8 kpre[6], vpre[5];
        if (more) {
#pragma unroll
            for (int i = 0; i < 6; ++i) {
                const int cid = t + i * 256;
                const int r = cid / 12, c = cid - r * 12;
                kpre[i] = *(const f16x8*)(kgbase + (long long)(kv0 + 128 + r) * AW + c * 8);
            }
#pragma unroll
            for (int i = 0; i < 5; ++i) {
                const int cid = t + i * 256;
                const int r = cid >> 4, c = cid & 15;
                vpre[i] = *(const f16x8*)(vgbase + (long long)r * LSEQ + kv0 + 128 + c * 8);
            }
        }

        // S^T = K @ Q^T over this wave's kv half: each kb feeds 2 m-frags.
        // sc[m][n][r] = S[q = wsub*32+m*16+l15][kv = kh*64 + n*16 + lhi*4 + r]
        f32x4 sc[2][4];
#pragma unroll
        for (int m = 0; m < 2; ++m)
#pragma unroll
            for (int n = 0; n < 4; ++n) sc[m][n] = (f32x4){0.f, 0.f, 0.f, 0.f};
        __builtin_amdgcn_s_setprio(1);
#pragma unroll
        for (int n = 0; n < 4; ++n)
#pragma unroll
            for (int ks = 0; ks < 3; ++ks) {
                f16x8 kb = *(const f16x8*)&Ks[kh * 64 + n * 16 + l15][ks * 32 + lhi * 8];
                sc[0][n] = __builtin_amdgcn_mfma_f32_16x16x32_f16(kb, qf[0][ks], sc[0][n], 0, 0, 0);
                sc[1][n] = __builtin_amdgcn_mfma_f32_16x16x32_f16(kb, qf[1][ks], sc[1][n], 0, 0, 0);
            }
        __builtin_amdgcn_s_setprio(0);

        // row max per m: local over 16 + 2 shfl
        float mr[2];
#pragma unroll
        for (int m = 0; m < 2; ++m) {
            float mm = sc[m][0][0];
#pragma unroll
            for (int n = 0; n < 4; ++n)
#pragma unroll
                for (int r = 0; r < 4; ++r) mm = fmaxf(mm, sc[m][n][r]);
            mm = fmaxf(mm, __shfl_xor(mm, 16));
            mm = fmaxf(mm, __shfl_xor(mm, 32));
            mr[m] = mm;
        }
        const bool nog = (mr[0] <= M[0] + 8.f) && (mr[1] <= M[1] + 8.f);
        if (__all(nog)) {
#pragma unroll
            for (int m = 0; m < 2; ++m) {
                float rsum = 0.f;
#pragma unroll
                for (int n = 0; n < 4; ++n)
#pragma unroll
                    for (int r = 0; r < 4; ++r) {
                        const float p = __expf(sc[m][n][r] - M[m]);
                        sc[m][n][r] = p;
                        rsum += p;
                    }
                rsum += __shfl_xor(rsum, 16);
                rsum += __shfl_xor(rsum, 32);
                L[m] += rsum;
            }
        } else {
            float ss[2];
#pragma unroll
            for (int m = 0; m < 2; ++m) {
                const float nm = fmaxf(M[m], mr[m]);
                ss[m] = __expf(M[m] - nm);
                M[m] = nm;
                float rsum = 0.f;
#pragma unroll
                for (int n = 0; n < 4; ++n)
#pragma unroll
                    for (int r = 0; r < 4; ++r) {
                        const float p = __expf(sc[m][n][r] - M[m]);
                        sc[m][n][r] = p;
                        rsum += p;
                    }
                rsum += __shfl_xor(rsum, 16);
                rsum += __shfl_xor(rsum, 32);
                L[m] = L[m] * ss[m] + rsum;
            }
#pragma unroll
            for (int m = 0; m < 2; ++m)
#pragma unroll
                for (int r = 0; r < 4; ++r) {
                    const float sr = __shfl(ss[m], lhi * 4 + r);
#pragma unroll
                    for (int nv = 0; nv < 5; ++nv) Oacc[m][nv][r] *= sr;
                }
        }

        // P -> LDS quadrant (own wave's rows x own kv half)
#pragma unroll
        for (int m = 0; m < 2; ++m)
#pragma unroll
            for (int n = 0; n < 4; ++n) {
                f16x4v pv = { (f16)sc[m][n][0], (f16)sc[m][n][1],
                              (f16)sc[m][n][2], (f16)sc[m][n][3] };
                *(f16x4v*)&Ps[wsub * 32 + m * 16 + l15][kh * 64 + n * 16 + lhi * 4] = pv;
            }

        f16x8 pa[2][2];
#pragma unroll
        for (int m = 0; m < 2; ++m)
#pragma unroll
            for (int k2i = 0; k2i < 2; ++k2i)
                pa[m][k2i] = *(const f16x8*)&Ps[wsub * 32 + m * 16 + l15][kh * 64 + k2i * 32 + lhi * 8];
        __builtin_amdgcn_s_setprio(1);
#pragma unroll
        for (int nv = 0; nv < 5; ++nv)
#pragma unroll
            for (int k2i = 0; k2i < 2; ++k2i) {
                f16x8 vb = *(const f16x8*)&Vs[nv * 16 + l15][kh * 64 + k2i * 32 + lhi * 8];
                Oacc[0][nv] = __builtin_amdgcn_mfma_f32_16x16x32_f16(pa[0][k2i], vb, Oacc[0][nv], 0, 0, 0);
                Oacc[1][nv] = __builtin_amdgcn_mfma_f32_16x16x32_f16(pa[1][k2i], vb, Oacc[1][nv], 0, 0, 0);
            }
        __builtin_amdgcn_s_setprio(0);
        __syncthreads();

        if (more) {
#pragma unroll
            for (int i = 0; i < 6; ++i) {
                const int cid = t + i * 256;
                const int r = cid / 12, c = cid - r * 12;
                *(f16x8*)&Ks[r][c * 8] = kpre[i];
            }
#pragma unroll
            for (int i = 0; i < 5; ++i) {
                const int cid = t + i * 256;
                const int r = cid >> 4, c = cid & 15;
                *(f16x8*)&Vs[r][c * 8] = vpre[i];
            }
        }
        __syncthreads();
    }

    // ---- in-block merge of the two kv halves (LDS aliases dead Ks) ----
    float* O1  = (float*)&Ks[0][0];      // [64][84] f32
    float* ML1 = O1 + 64 * 84;           // [64][2]
    if (kh == 1) {
#pragma unroll
        for (int m = 0; m < 2; ++m) {
#pragma unroll
            for (int nv = 0; nv < 5; ++nv)
#pragma unroll
                for (int r = 0; r < 4; ++r)
                    O1[(wsub * 32 + m * 16 + lhi * 4 + r) * 84 + nv * 16 + l15] = Oacc[m][nv][r];
            if (lhi == 0) {
                ML1[(wsub * 32 + m * 16 + l15) * 2 + 0] = M[m];
                ML1[(wsub * 32 + m * 16 + l15) * 2 + 1] = L[m];
            }
        }
    }
    __syncthreads();
    if (kh == 0) {
#pragma unroll
        for (int m = 0; m < 2; ++m)
#pragma unroll
            for (int r = 0; r < 4; ++r) {
                const int i = wsub * 32 + m * 16 + lhi * 4 + r;
                const float Mo = __shfl(M[m], lhi * 4 + r);
                const float Lo = __shfl(L[m], lhi * 4 + r);
                const float M1 = ML1[i * 2], L1v = ML1[i * 2 + 1];
                const float nm = fmaxf(Mo, M1);
                const float a0 = __expf(Mo - nm), a1 = __expf(M1 - nm);
                const float Lt = Lo * a0 + L1v * a1;
                const float inv = 1.0f / Lt;
                f16* orow = OCp + (((long long)(z * 16 + bh) * LSEQ) + q0 + i) * VW;
#pragma unroll
                for (int nv = 0; nv < 5; ++nv)
                    orow[nv * 16 + l15] =
                        (f16)((Oacc[m][nv][r] * a0 + O1[i * 84 + nv * 16 + l15] * a1) * inv);
                if (l15 == 0)
                    LSE[(long long)(z * 16 + bh) * LSEQ + q0 + i] = nm + __logf(Lt);
            }
    }
}

// ---------------------------------------------------------------------------
// Combine splits (LSE merge) + un-rotate + concat -> CC f16 [2048][608]
// ---------------------------------------------------------------------------
__global__ __launch_bounds__(256)
void combine_concat_kernel(const f16* __restrict__ OCp, const float* __restrict__ LSE,
                           const float* __restrict__ Rm, const float* __restrict__ tr,
                           f16* __restrict__ CC)
{
    const int bl0 = blockIdx.x * 4;
    const int b = bl0 >> 10;
    const int t = threadIdx.x;

    __shared__ float w1s[4][8], w2s[4][8];
    if (t < 32) {
        const int row = t >> 3, h = t & 7;
        const int l = (bl0 + row) & 1023;
        const int bh = b * 8 + h;
        const float l1 = LSE[(long long)bh * LSEQ + l];
        const float l2 = LSE[(long long)(16 + bh) * LSEQ + l];
        const float mm = fmaxf(l1, l2);
        const float e1 = __expf(l1 - mm), e2 = __expf(l2 - mm);
        const float inv = 1.0f / (e1 + e2);
        w1s[row][h] = e1 * inv; w2s[row][h] = e2 * inv;
    }
    __syncthreads();

    for (int idx = t; idx < 2048; idx += 256) {
        const int row = idx >> 9, c = idx & 511;
        const int h = c >> 6, ch = c & 63;
        const int l = (bl0 + row) & 1023;
        const long long base = ((long long)(b * 8 + h) * LSEQ + l) * VW + ch;
        const float v = w1s[row][h] * (float)OCp[base] + w2s[row][h] * (float)OCp[OCPSTR + base];
        CC[(long long)(bl0 + row) * ODIM + c] = (f16)v;
    }
    if (t < 128) {
        const int row = t >> 5, h = (t >> 2) & 7, p = t & 3;
        const int bl = bl0 + row, l = bl & 1023;
        const long long base = ((long long)(b * 8 + h) * LSEQ + l) * VW + 64 + p * 3;
        const float w1 = w1s[row][h], w2 = w2s[row][h];
        float o[3];
#pragma unroll
        for (int c = 0; c < 3; ++c)
            o[c] = w1 * (float)OCp[base + c] + w2 * (float)OCp[OCPSTR + base + c]
                 - tr[(long long)bl * 3 + c];
        const float* Rr = Rm + (long long)bl * 9;
        f16* crow = CC + (long long)bl * ODIM + 512 + h * 12 + p * 3;
        crow[0] = (f16)(Rr[0]*o[0] + Rr[3]*o[1] + Rr[6]*o[2]);
        crow[1] = (f16)(Rr[1]*o[0] + Rr[4]*o[1] + Rr[7]*o[2]);
        crow[2] = (f16)(Rr[2]*o[0] + Rr[5]*o[1] + Rr[8]*o[2]);
    }
}

// ---------------------------------------------------------------------------
// out = LayerNorm(s + Y + bo) * gamma + beta
// ---------------------------------------------------------------------------
__global__ __launch_bounds__(256)
void residual_ln_kernel(const float* __restrict__ s, const float* __restrict__ Y,
                        const float* __restrict__ bo, const float* __restrict__ gamma,
                        const float* __restrict__ beta, float* __restrict__ out)
{
    const int bl = blockIdx.x;
    const int t = threadIdx.x;
    const float* srow = s + (long long)bl * DMODEL;
    const float* yrow = Y + (long long)bl * DMODEL;

    const float v0 = srow[t]       + yrow[t]       + bo[t];
    const float v1 = srow[t + 256] + yrow[t + 256] + bo[t + 256];

    float sum = v0 + v1, sq = v0 * v0 + v1 * v1;
#pragma unroll
    for (int o = 32; o > 0; o >>= 1) {
        sum += __shfl_xor(sum, o);
        sq  += __shfl_xor(sq,  o);
    }
    __shared__ float rs[4], rq[4];
    const int wid = t >> 6, lane = t & 63;
    if (lane == 0) { rs[wid] = sum; rq[wid] = sq; }
    __syncthreads();
    sum = rs[0] + rs[1] + rs[2] + rs[3];
    sq  = rq[0] + rq[1] + rq[2] + rq[3];

    const float mu  = sum * (1.0f / DMODEL);
    const float var = sq * (1.0f / DMODEL) - mu * mu;
    const float inv = rsqrtf(var + 1e-5f);

    out[(long long)bl * DMODEL + t]       = (v0 - mu) * inv * gamma[t]       + beta[t];
    out[(long long)bl * DMODEL + t + 256] = (v1 - mu) * inv * gamma[t + 256] + beta[t + 256];
}

// ---------------------------------------------------------------------------
extern "C" void kernel_launch(void* const* d_in, const int* in_sizes, int n_in,
                              void* d_out, int out_size, void* d_ws, size_t ws_size,
                              hipStream_t stream)
{
    const float* s    = (const float*)d_in[0];
    const float* R    = (const float*)d_in[1];
    const float* tr   = (const float*)d_in[2];
    const float* Wq   = (const float*)d_in[3];
    const float* Wk   = (const float*)d_in[4];
    const float* Wv   = (const float*)d_in[5];
    const float* Wqp  = (const float*)d_in[6];
    const float* Wkp  = (const float*)d_in[7];
    const float* Wvp  = (const float*)d_in[8];
    const float* Wo   = (const float*)d_in[9];
    const float* bo   = (const float*)d_in[10];
    const float* gam  = (const float*)d_in[11];
    const float* bet  = (const float*)d_in[12];
    const float* wC   = (const float*)d_in[13];
    float* out = (float*)d_out;

    // workspace layout
    f16* WallT = (f16*)d_ws;                       // 933,888
    f16* WoT   = WallT + 933888;                   // 311,296
    f16* P     = WoT + 311296;                     // 3,735,552
    f16* QA    = P + 3735552;                      // 1,572,864
    f16* KA    = QA + 1572864;                     // 1,572,864
    f16* VCT   = KA + 1572864;                     // 1,310,720
    f16* OCp   = VCT + 1310720;                    // 2,621,440 f16 (2 splits)
    float* LSE = (float*)(OCp + 2621440);          // 32,768 f32
    f16* CC    = (f16*)(LSE + 32768);              // 1,245,184
    float* Y   = (float*)(CC + 1245184);           // 1,048,576 f32

    const dim3 blk(256);

    prep_kernel<<<dim3(912), blk, 0, stream>>>(Wq, Wk, Wv, Wqp, Wkp, Wvp, WallT);

    // projections (+ WoT transpose side-blocks)
    proj_kernel<<<dim3(19, 34), blk, 0, stream>>>(s, WallT, Wo, WoT, P);

    build_aug2_kernel<<<dim3(16, 16), blk, 0, stream>>>(P, R, tr, wC, QA, KA, VCT);

    attn_kernel<<<dim3(16, 16, NSPLIT), blk, 0, stream>>>(QA, KA, VCT, OCp, LSE);

    combine_concat_kernel<<<dim3(512), blk, 0, stream>>>(OCp, LSE, R, tr, CC);

    // output projection: Y = CC @ WoT^T  (M=2048, N=512, K=608)
    gemm2_kernel<64, false><<<dim3(8, 32), blk, 0, stream>>>(CC, WoT, Y, 608, 512);

    residual_ln_kernel<<<dim3(BLTOT), blk, 0, stream>>>(s, Y, bo, gam, bet, out);
}

// Round 15
// 70.670 us; speedup vs baseline: 1.2772x; 1.2772x over previous
//
#include <hip/hip_runtime.h>
#include <hip/hip_fp16.h>
#include <math.h>

typedef _Float16 f16;
typedef _Float16 f16x8 __attribute__((ext_vector_type(8)));
typedef _Float16 f16x4v __attribute__((ext_vector_type(4)));
typedef float f32x4 __attribute__((ext_vector_type(4)));

#define BATCH   2
#define LSEQ    1024
#define BLTOT   2048
#define DMODEL  512
#define NHEAD   8
#define PDIM    1824          // 512*3 + 96*3
#define AW      96            // QK augmented width (78 used, padded to 96)
#define VW      80            // V/O width (76 used, padded to 80)
#define ODIM    608
#define NSPLIT  2
#define OCPSTR  1310720       // f16 elements per split of OCp (16*1024*80)

// ---------------------------------------------------------------------------
// Prep: WallT tiles only (912 blocks).
// ---------------------------------------------------------------------------
__global__ __launch_bounds__(256)
void prep_kernel(const float* __restrict__ Wq, const float* __restrict__ Wk,
                 const float* __restrict__ Wv, const float* __restrict__ Wqp,
                 const float* __restrict__ Wkp, const float* __restrict__ Wvp,
                 f16* __restrict__ WallT)
{
    const int blk = blockIdx.x;
    const int t = threadIdx.x;
    __shared__ float tile[32][33];

    const int n0 = (blk % 57) * 32, k0 = (blk / 57) * 32;
    const float* src; int ld, nc0;
    if      (n0 < 512)  { src = Wq;  ld = 512; nc0 = n0; }
    else if (n0 < 1024) { src = Wk;  ld = 512; nc0 = n0 - 512; }
    else if (n0 < 1536) { src = Wv;  ld = 512; nc0 = n0 - 1024; }
    else if (n0 < 1632) { src = Wqp; ld = 96;  nc0 = n0 - 1536; }
    else if (n0 < 1728) { src = Wkp; ld = 96;  nc0 = n0 - 1632; }
    else                { src = Wvp; ld = 96;  nc0 = n0 - 1728; }
#pragma unroll
    for (int i = 0; i < 4; ++i) {
        const int idx2 = t + i * 256;
        const int kl = idx2 >> 5, nl = idx2 & 31;
        tile[kl][nl] = src[(long long)(k0 + kl) * ld + nc0 + nl];
    }
    __syncthreads();
#pragma unroll
    for (int i = 0; i < 4; ++i) {
        const int idx2 = t + i * 256;
        const int nl = idx2 >> 5, kl = idx2 & 31;
        WallT[(long long)(n0 + nl) * 512 + k0 + kl] = (f16)tile[kl][nl];
    }
}

// ---------------------------------------------------------------------------
// Projection GEMM (+WoT transpose side-blocks). y<32: P = s(f32) @ WallT^T.
// y in {32,33}: 8 WoT transpose tiles each. Tile 64x96, BK=32, dbuf.
// A staged f32->f16 with in-register convert (vectorized loads + f16x8 writes).
// ---------------------------------------------------------------------------
__global__ __launch_bounds__(256)
void proj_kernel(const float* __restrict__ S, const f16* __restrict__ Bt,
                 const float* __restrict__ Wo, f16* __restrict__ WoT,
                 f16* __restrict__ P)
{
    __shared__ f16 As[2][64][40];
    __shared__ f16 Bs[2][96][40];
    const int t = threadIdx.x;

    if (blockIdx.y >= 32) {
        float (*tile)[33] = (float(*)[33])&As[0][0][0];
        const int base = (blockIdx.x + (blockIdx.y - 32) * 19) * 8;
#pragma unroll 1
        for (int it = 0; it < 8; ++it) {
            const int idx = base + it;
            const int n0 = (idx & 15) * 32, k0 = (idx >> 4) * 32;
#pragma unroll
            for (int i = 0; i < 4; ++i) {
                const int idx2 = t + i * 256;
                const int kl = idx2 >> 5, nl = idx2 & 31;
                tile[kl][nl] = Wo[(long long)(k0 + kl) * 512 + n0 + nl];
            }
            __syncthreads();
#pragma unroll
            for (int i = 0; i < 4; ++i) {
                const int idx2 = t + i * 256;
                const int nl = idx2 >> 5, kl = idx2 & 31;
                WoT[(long long)(n0 + nl) * 608 + k0 + kl] = (f16)tile[kl][nl];
            }
            __syncthreads();
        }
        return;
    }

    const int w = t >> 6, lane = t & 63, l15 = lane & 15, lhi = lane >> 4;
    const int row0 = blockIdx.y * 64, col0 = blockIdx.x * 96;
    const int ar = t >> 2, ac = t & 3;
    const int K = 512;

    f32x4 acc[6];
#pragma unroll
    for (int n = 0; n < 6; ++n) acc[n] = (f32x4){0.f, 0.f, 0.f, 0.f};

    float4 a0, a1;
    f16x8 bR[2];
    a0 = *(const float4*)&S[(long long)(row0 + ar) * K + ac * 8];
    a1 = *(const float4*)&S[(long long)(row0 + ar) * K + ac * 8 + 4];
#pragma unroll
    for (int i = 0; i < 2; ++i) {
        const int cid = t + i * 256;
        if (cid < 384) {
            const int br = cid >> 2, bc = cid & 3;
            bR[i] = *(const f16x8*)&Bt[(long long)(col0 + br) * K + bc * 8];
        }
    }
    {
        f16x8 v = { (f16)a0.x, (f16)a0.y, (f16)a0.z, (f16)a0.w,
                    (f16)a1.x, (f16)a1.y, (f16)a1.z, (f16)a1.w };
        *(f16x8*)&As[0][ar][ac * 8] = v;
    }
#pragma unroll
    for (int i = 0; i < 2; ++i) {
        const int cid = t + i * 256;
        if (cid < 384) *(f16x8*)&Bs[0][cid >> 2][(cid & 3) * 8] = bR[i];
    }
    __syncthreads();

    for (int st = 0; st < 16; ++st) {
        const int cur = st & 1;
        if (st + 1 < 16) {
            const int k0 = (st + 1) << 5;
            a0 = *(const float4*)&S[(long long)(row0 + ar) * K + k0 + ac * 8];
            a1 = *(const float4*)&S[(long long)(row0 + ar) * K + k0 + ac * 8 + 4];
#pragma unroll
            for (int i = 0; i < 2; ++i) {
                const int cid = t + i * 256;
                if (cid < 384) {
                    const int br = cid >> 2, bc = cid & 3;
                    bR[i] = *(const f16x8*)&Bt[(long long)(col0 + br) * K + k0 + bc * 8];
                }
            }
        }
        f16x8 af = *(const f16x8*)&As[cur][w * 16 + l15][lhi * 8];
        f16x8 bf[6];
#pragma unroll
        for (int n = 0; n < 6; ++n)
            bf[n] = *(const f16x8*)&Bs[cur][n * 16 + l15][lhi * 8];
#pragma unroll
        for (int n = 0; n < 6; ++n)
            acc[n] = __builtin_amdgcn_mfma_f32_16x16x32_f16(af, bf[n], acc[n], 0, 0, 0);
        if (st + 1 < 16) {
            f16x8 v = { (f16)a0.x, (f16)a0.y, (f16)a0.z, (f16)a0.w,
                        (f16)a1.x, (f16)a1.y, (f16)a1.z, (f16)a1.w };
            *(f16x8*)&As[cur ^ 1][ar][ac * 8] = v;
#pragma unroll
            for (int i = 0; i < 2; ++i) {
                const int cid = t + i * 256;
                if (cid < 384) *(f16x8*)&Bs[cur ^ 1][cid >> 2][(cid & 3) * 8] = bR[i];
            }
        }
        __syncthreads();
    }

    const int row = row0 + w * 16 + lhi * 4;
#pragma unroll
    for (int n = 0; n < 6; ++n) {
        const int col = col0 + n * 16 + l15;
#pragma unroll
        for (int r = 0; r < 4; ++r)
            P[(long long)(row + r) * PDIM + col] = (f16)acc[n][r];
    }
}

// ---------------------------------------------------------------------------
// Double-buffered MFMA f16 GEMM (out projection).  C = A @ Bt^T.
// Tile 64 x BN, BK=32, 4 waves each 16 rows.
// ---------------------------------------------------------------------------
template<int BN, bool OUT16>
__global__ __launch_bounds__(256)
void gemm2_kernel(const f16* __restrict__ A, const f16* __restrict__ Bt,
                  void* __restrict__ Cout, int K, int ldc)
{
    constexpr int BCH = (BN * 4 + 255) / 256;
    __shared__ f16 As[2][64][40];
    __shared__ f16 Bs[2][BN][40];
    const int t = threadIdx.x;
    const int w = t >> 6, lane = t & 63, l15 = lane & 15, lhi = lane >> 4;
    const int row0 = blockIdx.y * 64, col0 = blockIdx.x * BN;
    const int ar = t >> 2, ac = t & 3;

    f32x4 acc[BN / 16];
#pragma unroll
    for (int n = 0; n < BN / 16; ++n) acc[n] = (f32x4){0.f, 0.f, 0.f, 0.f};

    const int nsteps = K >> 5;

    f16x8 aR;
    f16x8 bR[BCH];
    aR = *(const f16x8*)&A[(long long)(row0 + ar) * K + ac * 8];
#pragma unroll
    for (int i = 0; i < BCH; ++i) {
        const int cid = t + i * 256;
        if (cid < BN * 4) {
            const int br = cid >> 2, bc = cid & 3;
            bR[i] = *(const f16x8*)&Bt[(long long)(col0 + br) * K + bc * 8];
        }
    }
    *(f16x8*)&As[0][ar][ac * 8] = aR;
#pragma unroll
    for (int i = 0; i < BCH; ++i) {
        const int cid = t + i * 256;
        if (cid < BN * 4) *(f16x8*)&Bs[0][cid >> 2][(cid & 3) * 8] = bR[i];
    }
    __syncthreads();

    for (int st = 0; st < nsteps; ++st) {
        const int cur = st & 1;
        if (st + 1 < nsteps) {
            const int k0 = (st + 1) << 5;
            aR = *(const f16x8*)&A[(long long)(row0 + ar) * K + k0 + ac * 8];
#pragma unroll
            for (int i = 0; i < BCH; ++i) {
                const int cid = t + i * 256;
                if (cid < BN * 4) {
                    const int br = cid >> 2, bc = cid & 3;
                    bR[i] = *(const f16x8*)&Bt[(long long)(col0 + br) * K + k0 + bc * 8];
                }
            }
        }
        f16x8 af = *(const f16x8*)&As[cur][w * 16 + l15][lhi * 8];
        f16x8 bf[BN / 16];
#pragma unroll
        for (int n = 0; n < BN / 16; ++n)
            bf[n] = *(const f16x8*)&Bs[cur][n * 16 + l15][lhi * 8];
#pragma unroll
        for (int n = 0; n < BN / 16; ++n)
            acc[n] = __builtin_amdgcn_mfma_f32_16x16x32_f16(af, bf[n], acc[n], 0, 0, 0);
        if (st + 1 < nsteps) {
            *(f16x8*)&As[cur ^ 1][ar][ac * 8] = aR;
#pragma unroll
            for (int i = 0; i < BCH; ++i) {
                const int cid = t + i * 256;
                if (cid < BN * 4) *(f16x8*)&Bs[cur ^ 1][cid >> 2][(cid & 3) * 8] = bR[i];
            }
        }
        __syncthreads();
    }

    const int row = row0 + w * 16 + lhi * 4;
#pragma unroll
    for (int n = 0; n < BN / 16; ++n) {
        const int col = col0 + n * 16 + l15;
#pragma unroll
        for (int r = 0; r < 4; ++r) {
            if (OUT16) ((f16*)Cout)[(long long)(row + r) * ldc + col] = (f16)acc[n][r];
            else       ((float*)Cout)[(long long)(row + r) * ldc + col] = acc[n][r];
        }
    }
}

// ---------------------------------------------------------------------------
// Fused augment+transpose. Grid (16 l-tiles of 64, 16 bh). Produces
// QA/KA f16 [bh][1024][96], VCT f16 [bh][80][1024].
// KOFF folded into KA cols 76/77 (hi+residual, exact): QA[76]=QA[77]=1,
// KA[76]=-f16(koff), KA[77]=-(koff - f16(koff)).
// ---------------------------------------------------------------------------
__global__ __launch_bounds__(256)
void build_aug2_kernel(const f16* __restrict__ P, const float* __restrict__ Rm,
                       const float* __restrict__ tr, const float* __restrict__ wC,
                       f16* __restrict__ QA, f16* __restrict__ KA,
                       f16* __restrict__ VCT)
{
    const int l0 = blockIdx.x * 64;
    const int bh = blockIdx.y;
    const int b = bh >> 3, h = bh & 7;
    const int t = threadIdx.x;

    __shared__ float Rl[64][9];
    __shared__ float trl[64][3];
    __shared__ f16 gq[64][12];
    __shared__ f16 gk[64][12];
    __shared__ float k2[64][4];
    __shared__ f16 Vt[VW][72];
    __shared__ float wcs;

    const long long blbase = (long long)b * LSEQ + l0;

    for (int i = t; i < 64 * 9; i += 256) Rl[i / 9][i % 9] = Rm[blbase * 9 + i];
    for (int i = t; i < 64 * 3; i += 256) trl[i / 3][i % 3] = tr[blbase * 3 + i];
    if (t == 0) { float x = wC[h]; wcs = log1pf(expf(x)); }
    __syncthreads();
    const float wc = wcs;

    for (int i = t; i < 768; i += 256) {
        const int l = i / 12, pp = i - l * 12;
        const int proj = pp >> 2, p = pp & 3;
        const f16* src = P + (blbase + l) * PDIM + 1536 + proj * 96 + h * 12 + p * 3;
        const float x = (float)src[0], y = (float)src[1], z = (float)src[2];
        const float gx = Rl[l][0]*x + Rl[l][1]*y + Rl[l][2]*z + trl[l][0];
        const float gy = Rl[l][3]*x + Rl[l][4]*y + Rl[l][5]*z + trl[l][1];
        const float gz = Rl[l][6]*x + Rl[l][7]*y + Rl[l][8]*z + trl[l][2];
        if (proj == 0) {
            gq[l][p * 3 + 0] = (f16)(wc * gx);
            gq[l][p * 3 + 1] = (f16)(wc * gy);
            gq[l][p * 3 + 2] = (f16)(wc * gz);
        } else if (proj == 1) {
            gk[l][p * 3 + 0] = (f16)gx;
            gk[l][p * 3 + 1] = (f16)gy;
            gk[l][p * 3 + 2] = (f16)gz;
            k2[l][p] = gx * gx + gy * gy + gz * gz;
        } else {
            Vt[64 + p * 3 + 0][l] = (f16)gx;
            Vt[64 + p * 3 + 1][l] = (f16)gy;
            Vt[64 + p * 3 + 2][l] = (f16)gz;
        }
    }
    for (int i = t; i < 512; i += 256) {
        const int l = i >> 3, ch = i & 7;
        f16x8 v = *(const f16x8*)&P[(blbase + l) * PDIM + 1024 + h * 64 + ch * 8];
#pragma unroll
        for (int j = 0; j < 8; ++j) Vt[ch * 8 + j][l] = v[j];
    }
    for (int i = t; i < 36; i += 256) {
        const int r = 76 + i / 9, ch = i % 9;
        *(f16x8*)&Vt[r][ch * 8] = (f16x8){0,0,0,0,0,0,0,0};
    }
    __syncthreads();

    for (int i = t; i < 768; i += 256) {
        const int l = i / 12, ch = i - l * 12;
        const long long prow = (blbase + l) * PDIM;
        const long long orow = ((long long)bh * LSEQ + l0 + l) * AW;
        f16x8 q, k;
        if (ch < 8) {
            f16x8 qv = *(const f16x8*)&P[prow + h * 64 + ch * 8];
            f16x8 kv = *(const f16x8*)&P[prow + 512 + h * 64 + ch * 8];
            q = qv * (f16)0.125f;
            k = kv;
        } else if (ch == 8) {
#pragma unroll
            for (int j = 0; j < 8; ++j) { q[j] = gq[l][j]; k[j] = gk[l][j]; }
        } else if (ch == 9) {
            const float koff = 0.5f * wc * (k2[l][0] + k2[l][1] + k2[l][2] + k2[l][3]);
            const f16 kh = (f16)koff;
            const float kres = koff - (float)kh;
#pragma unroll
            for (int j = 0; j < 4; ++j) { q[j] = gq[l][8 + j]; k[j] = gk[l][8 + j]; }
            q[4] = (f16)1.f; k[4] = -kh;          // col 76
            q[5] = (f16)1.f; k[5] = (f16)(-kres); // col 77
            q[6] = (f16)0.f; k[6] = (f16)0.f;
            q[7] = (f16)0.f; k[7] = (f16)0.f;
        } else {
            q = (f16x8){0,0,0,0,0,0,0,0};
            k = (f16x8){0,0,0,0,0,0,0,0};
        }
        *(f16x8*)&QA[orow + ch * 8] = q;
        *(f16x8*)&KA[orow + ch * 8] = k;
    }
    for (int i = t; i < 640; i += 256) {
        const int c = i >> 3, lg = i & 7;
        *(f16x8*)&VCT[((long long)bh * VW + c) * LSEQ + l0 + lg * 8] =
            *(const f16x8*)&Vt[c][lg * 8];
    }
}

// ---------------------------------------------------------------------------
// Fused flash attention, split-KV, register-prefetch double buffer, defer-max,
// SWAPPED QK^T (S^T = K x Q): each thread owns one q-row's 32 k-scores.
// KOFF folded into KA cols 76/77. Grid (16 q-tiles, 16 bh, NSPLIT).
// Outputs NORMALIZED O (f16) + LSE (f32).
// ---------------------------------------------------------------------------
__global__ __launch_bounds__(256, 2)
void attn_kernel(const f16* __restrict__ QA, const f16* __restrict__ KA,
                 const f16* __restrict__ VCT,
                 f16* __restrict__ OCp, float* __restrict__ LSE)
{
    const int bh = blockIdx.y;
    const int q0 = blockIdx.x * 64;
    const int z  = blockIdx.z;
    const int t = threadIdx.x;
    const int w = t >> 6, lane = t & 63, l15 = lane & 15, lhi = lane >> 4;

    __shared__ f16 Ks[128][104];
    __shared__ f16 Vs[VW][136];
    __shared__ f16 Ps[64][136];

    const f16* qbase = QA + ((long long)bh * LSEQ + q0 + w * 16 + l15) * AW;
    f16x8 qf[3];
#pragma unroll
    for (int ks = 0; ks < 3; ++ks)
        qf[ks] = *(const f16x8*)(qbase + ks * 32 + lhi * 8);

    f32x4 Oacc[5];
#pragma unroll
    for (int nv = 0; nv < 5; ++nv) Oacc[nv] = (f32x4){0.f, 0.f, 0.f, 0.f};
    float M = -1e30f, L = 0.f;     // per-thread state for q-row w*16+l15

    const f16* kgbase = KA + (long long)bh * LSEQ * AW;
    const f16* vgbase = VCT + (long long)bh * VW * LSEQ;

    const int kvbeg = z * (LSEQ / NSPLIT);
    const int kvend = kvbeg + LSEQ / NSPLIT;

#pragma unroll
    for (int i = 0; i < 6; ++i) {
        const int cid = t + i * 256;
        const int r = cid / 12, c = cid - r * 12;
        *(f16x8*)&Ks[r][c * 8] = *(const f16x8*)(kgbase + (long long)(kvbeg + r) * AW + c * 8);
    }
#pragma unroll
    for (int i = 0; i < 5; ++i) {
        const int cid = t + i * 256;
        const int r = cid >> 4, c = cid & 15;
        *(f16x8*)&Vs[r][c * 8] = *(const f16x8*)(vgbase + (long long)r * LSEQ + kvbeg + c * 8);
    }
    __syncthreads();

    for (int kv0 = kvbeg; kv0 < kvend; kv0 += 128) {
        const bool more = (kv0 + 128 < kvend);
        f16x8 kpre[6], vpre[5];
        if (more) {
#pragma unroll
            for (int i = 0; i < 6; ++i) {
                const int cid = t + i * 256;
                const int r = cid / 12, c = cid - r * 12;
                kpre[i] = *(const f16x8*)(kgbase + (long long)(kv0 + 128 + r) * AW + c * 8);
            }
#pragma unroll
            for (int i = 0; i < 5; ++i) {
                const int cid = t + i * 256;
                const int r = cid >> 4, c = cid & 15;
                vpre[i] = *(const f16x8*)(vgbase + (long long)r * LSEQ + kv0 + 128 + c * 8);
            }
        }

        // S^T = K @ Q^T : sc[n][r] = S[q = w*16+l15][k = n*16 + lhi*4 + r]
        f32x4 sc[8];
#pragma unroll
        for (int n = 0; n < 8; ++n) sc[n] = (f32x4){0.f, 0.f, 0.f, 0.f};
        __builtin_amdgcn_s_setprio(1);
#pragma unroll
        for (int n = 0; n < 8; ++n)
#pragma unroll
            for (int ks = 0; ks < 3; ++ks) {
                f16x8 kb = *(const f16x8*)&Ks[n * 16 + l15][ks * 32 + lhi * 8];
                sc[n] = __builtin_amdgcn_mfma_f32_16x16x32_f16(kb, qf[ks], sc[n], 0, 0, 0);
            }
        __builtin_amdgcn_s_setprio(0);

        // row max: local over 32 + 2 shfl (across lanes sharing l15)
        float mr = sc[0][0];
#pragma unroll
        for (int n = 0; n < 8; ++n)
#pragma unroll
            for (int r = 0; r < 4; ++r) mr = fmaxf(mr, sc[n][r]);
        mr = fmaxf(mr, __shfl_xor(mr, 16));
        mr = fmaxf(mr, __shfl_xor(mr, 32));

        const bool nog = (mr <= M + 8.f);
        float rsum = 0.f;
        if (__all(nog)) {
            // defer: M unchanged, no rescale (P bounded by e^8)
#pragma unroll
            for (int n = 0; n < 8; ++n)
#pragma unroll
                for (int r = 0; r < 4; ++r) {
                    const float p = __expf(sc[n][r] - M);
                    sc[n][r] = p;
                    rsum += p;
                }
            rsum += __shfl_xor(rsum, 16);
            rsum += __shfl_xor(rsum, 32);
            L += rsum;
        } else {
            const float nm = fmaxf(M, mr);
            const float ss = __expf(M - nm);
            M = nm;
#pragma unroll
            for (int n = 0; n < 8; ++n)
#pragma unroll
                for (int r = 0; r < 4; ++r) {
                    const float p = __expf(sc[n][r] - M);
                    sc[n][r] = p;
                    rsum += p;
                }
            rsum += __shfl_xor(rsum, 16);
            rsum += __shfl_xor(rsum, 32);
            L = L * ss + rsum;
            // redistribute scale to O-rows (O rows are q = w*16 + lhi*4 + r)
            float sr[4];
#pragma unroll
            for (int r = 0; r < 4; ++r) sr[r] = __shfl(ss, lhi * 4 + r);
#pragma unroll
            for (int nv = 0; nv < 5; ++nv)
#pragma unroll
                for (int r = 0; r < 4; ++r) Oacc[nv][r] *= sr[r];
        }

        // P -> LDS: packed 4-consecutive-k writes into row q = w*16+l15
#pragma unroll
        for (int n = 0; n < 8; ++n) {
            f16x4v pv = { (f16)sc[n][0], (f16)sc[n][1], (f16)sc[n][2], (f16)sc[n][3] };
            *(f16x4v*)&Ps[w * 16 + l15][n * 16 + lhi * 4] = pv;
        }

        f16x8 pa[4];
#pragma unroll
        for (int ks = 0; ks < 4; ++ks)
            pa[ks] = *(const f16x8*)&Ps[w * 16 + l15][ks * 32 + lhi * 8];
        __builtin_amdgcn_s_setprio(1);
#pragma unroll
        for (int nv = 0; nv < 5; ++nv)
#pragma unroll
            for (int ks = 0; ks < 4; ++ks) {
                f16x8 vb = *(const f16x8*)&Vs[nv * 16 + l15][ks * 32 + lhi * 8];
                Oacc[nv] = __builtin_amdgcn_mfma_f32_16x16x32_f16(pa[ks], vb, Oacc[nv], 0, 0, 0);
            }
        __builtin_amdgcn_s_setprio(0);
        __syncthreads();

        if (more) {
#pragma unroll
            for (int i = 0; i < 6; ++i) {
                const int cid = t + i * 256;
                const int r = cid / 12, c = cid - r * 12;
                *(f16x8*)&Ks[r][c * 8] = kpre[i];
            }
#pragma unroll
            for (int i = 0; i < 5; ++i) {
                const int cid = t + i * 256;
                const int r = cid >> 4, c = cid & 15;
                *(f16x8*)&Vs[r][c * 8] = vpre[i];
            }
        }
        __syncthreads();
    }

    // epilogue: O rows are q = w*16 + lhi*4 + r; fetch their L via shfl
    float invr[4];
#pragma unroll
    for (int r = 0; r < 4; ++r) {
        const float Lr = __shfl(L, lhi * 4 + r);
        invr[r] = 1.0f / Lr;
    }
    f16* obase = OCp + (((long long)(z * 16 + bh) * LSEQ) + q0 + w * 16 + lhi * 4) * VW;
#pragma unroll
    for (int nv = 0; nv < 5; ++nv)
#pragma unroll
        for (int r = 0; r < 4; ++r)
            obase[r * VW + nv * 16 + l15] = (f16)(Oacc[nv][r] * invr[r]);
    if (lhi == 0) {
        LSE[(long long)(z * 16 + bh) * LSEQ + q0 + w * 16 + l15] = M + __logf(L);
    }
}

// ---------------------------------------------------------------------------
// Combine splits (LSE merge) + un-rotate + concat -> CC f16 [2048][608]
// 4 rows per block, grid 512.
// ---------------------------------------------------------------------------
__global__ __launch_bounds__(256)
void combine_concat_kernel(const f16* __restrict__ OCp, const float* __restrict__ LSE,
                           const float* __restrict__ Rm, const float* __restrict__ tr,
                           f16* __restrict__ CC)
{
    const int bl0 = blockIdx.x * 4;
    const int b = bl0 >> 10;
    const int t = threadIdx.x;

    __shared__ float w1s[4][8], w2s[4][8];
    if (t < 32) {
        const int row = t >> 3, h = t & 7;
        const int l = (bl0 + row) & 1023;
        const int bh = b * 8 + h;
        const float l1 = LSE[(long long)bh * LSEQ + l];
        const float l2 = LSE[(long long)(16 + bh) * LSEQ + l];
        const float mm = fmaxf(l1, l2);
        const float e1 = __expf(l1 - mm), e2 = __expf(l2 - mm);
        const float inv = 1.0f / (e1 + e2);
        w1s[row][h] = e1 * inv; w2s[row][h] = e2 * inv;
    }
    __syncthreads();

    for (int idx = t; idx < 2048; idx += 256) {
        const int row = idx >> 9, c = idx & 511;
        const int h = c >> 6, ch = c & 63;
        const int l = (bl0 + row) & 1023;
        const long long base = ((long long)(b * 8 + h) * LSEQ + l) * VW + ch;
        const float v = w1s[row][h] * (float)OCp[base] + w2s[row][h] * (float)OCp[OCPSTR + base];
        CC[(long long)(bl0 + row) * ODIM + c] = (f16)v;
    }
    if (t < 128) {
        const int row = t >> 5, h = (t >> 2) & 7, p = t & 3;
        const int bl = bl0 + row, l = bl & 1023;
        const long long base = ((long long)(b * 8 + h) * LSEQ + l) * VW + 64 + p * 3;
        const float w1 = w1s[row][h], w2 = w2s[row][h];
        float o[3];
#pragma unroll
        for (int c = 0; c < 3; ++c)
            o[c] = w1 * (float)OCp[base + c] + w2 * (float)OCp[OCPSTR + base + c]
                 - tr[(long long)bl * 3 + c];
        const float* Rr = Rm + (long long)bl * 9;
        f16* crow = CC + (long long)bl * ODIM + 512 + h * 12 + p * 3;
        crow[0] = (f16)(Rr[0]*o[0] + Rr[3]*o[1] + Rr[6]*o[2]);
        crow[1] = (f16)(Rr[1]*o[0] + Rr[4]*o[1] + Rr[7]*o[2]);
        crow[2] = (f16)(Rr[2]*o[0] + Rr[5]*o[1] + Rr[8]*o[2]);
    }
}

// ---------------------------------------------------------------------------
// out = LayerNorm(s + Y + bo) * gamma + beta
// ---------------------------------------------------------------------------
__global__ __launch_bounds__(256)
void residual_ln_kernel(const float* __restrict__ s, const float* __restrict__ Y,
                        const float* __restrict__ bo, const float* __restrict__ gamma,
                        const float* __restrict__ beta, float* __restrict__ out)
{
    const int bl = blockIdx.x;
    const int t = threadIdx.x;
    const float* srow = s + (long long)bl * DMODEL;
    const float* yrow = Y + (long long)bl * DMODEL;

    const float v0 = srow[t]       + yrow[t]       + bo[t];
    const float v1 = srow[t + 256] + yrow[t + 256] + bo[t + 256];

    float sum = v0 + v1, sq = v0 * v0 + v1 * v1;
#pragma unroll
    for (int o = 32; o > 0; o >>= 1) {
        sum += __shfl_xor(sum, o);
        sq  += __shfl_xor(sq,  o);
    }
    __shared__ float rs[4], rq[4];
    const int wid = t >> 6, lane = t & 63;
    if (lane == 0) { rs[wid] = sum; rq[wid] = sq; }
    __syncthreads();
    sum = rs[0] + rs[1] + rs[2] + rs[3];
    sq  = rq[0] + rq[1] + rq[2] + rq[3];

    const float mu  = sum * (1.0f / DMODEL);
    const float var = sq * (1.0f / DMODEL) - mu * mu;
    const float inv = rsqrtf(var + 1e-5f);

    out[(long long)bl * DMODEL + t]       = (v0 - mu) * inv * gamma[t]       + beta[t];
    out[(long long)bl * DMODEL + t + 256] = (v1 - mu) * inv * gamma[t + 256] + beta[t + 256];
}

// ---------------------------------------------------------------------------
extern "C" void kernel_launch(void* const* d_in, const int* in_sizes, int n_in,
                              void* d_out, int out_size, void* d_ws, size_t ws_size,
                              hipStream_t stream)
{
    const float* s    = (const float*)d_in[0];
    const float* R    = (const float*)d_in[1];
    const float* tr   = (const float*)d_in[2];
    const float* Wq   = (const float*)d_in[3];
    const float* Wk   = (const float*)d_in[4];
    const float* Wv   = (const float*)d_in[5];
    const float* Wqp  = (const float*)d_in[6];
    const float* Wkp  = (const float*)d_in[7];
    const float* Wvp  = (const float*)d_in[8];
    const float* Wo   = (const float*)d_in[9];
    const float* bo   = (const float*)d_in[10];
    const float* gam  = (const float*)d_in[11];
    const float* bet  = (const float*)d_in[12];
    const float* wC   = (const float*)d_in[13];
    float* out = (float*)d_out;

    // workspace layout
    f16* WallT = (f16*)d_ws;                       // 933,888
    f16* WoT   = WallT + 933888;                   // 311,296
    f16* P     = WoT + 311296;                     // 3,735,552
    f16* QA    = P + 3735552;                      // 1,572,864
    f16* KA    = QA + 1572864;                     // 1,572,864
    f16* VCT   = KA + 1572864;                     // 1,310,720
    f16* OCp   = VCT + 1310720;                    // 2,621,440 f16 (2 splits)
    float* LSE = (float*)(OCp + 2621440);          // 32,768 f32
    f16* CC    = (f16*)(LSE + 32768);              // 1,245,184
    float* Y   = (float*)(CC + 1245184);           // 1,048,576 f32

    const dim3 blk(256);

    prep_kernel<<<dim3(912), blk, 0, stream>>>(Wq, Wk, Wv, Wqp, Wkp, Wvp, WallT);

    // projections (+ WoT transpose side-blocks)
    proj_kernel<<<dim3(19, 34), blk, 0, stream>>>(s, WallT, Wo, WoT, P);

    build_aug2_kernel<<<dim3(16, 16), blk, 0, stream>>>(P, R, tr, wC, QA, KA, VCT);

    attn_kernel<<<dim3(16, 16, NSPLIT), blk, 0, stream>>>(QA, KA, VCT, OCp, LSE);

    combine_concat_kernel<<<dim3(512), blk, 0, stream>>>(OCp, LSE, R, tr, CC);

    // output projection: Y = CC @ WoT^T  (M=2048, N=512, K=608)
    gemm2_kernel<64, false><<<dim3(8, 32), blk, 0, stream>>>(CC, WoT, Y, 608, 512);

    residual_ln_kernel<<<dim3(BLTOT), blk, 0, stream>>>(s, Y, bo, gam, bet, out);
}